// Round 3
// baseline (4240.681 us; speedup 1.0000x reference)
//
#include <hip/hip_runtime.h>
#include <hip/hip_bf16.h>

#define NUM_USER 300000
#define NUM_ITEM 200000
#define NTOT     (NUM_USER + NUM_ITEM)      // 500000
#define D        64
#define RPB      256                         // rows per bucket
#define NB       ((NTOT + RPB - 1) / RPB)    // 1954
#define NS       4                           // sub-cursors per bucket
#define NBS      (NB * NS)                   // 7816
#define PAD      16                          // ints per counter (64B line padding)

typedef __attribute__((ext_vector_type(8))) short bf16x8;
typedef __attribute__((ext_vector_type(4))) float f32x4;

__device__ __forceinline__ short f2bf(float f) {
    unsigned u = __float_as_uint(f);
    u += 0x7FFFu + ((u >> 16) & 1u);   // round-to-nearest-even
    return (short)(u >> 16);
}

// ---------- 1. histogram of (bucket, sub) counts, LDS-staged ----------
__global__ __launch_bounds__(256) void hist_kernel(
    const int* __restrict__ rows, int* __restrict__ gcnt, int nnz)
{
    __shared__ int lcnt[NBS];                 // 31.3 KB
    for (int i = threadIdx.x; i < NBS; i += 256) lcnt[i] = 0;
    __syncthreads();
    int stride = gridDim.x * 256;
    for (int e = blockIdx.x * 256 + threadIdx.x; e < nnz; e += stride) {
        int r = rows[e];
        int bs = ((r >> 8) << 2) | ((e >> 12) & 3);
        atomicAdd(&lcnt[bs], 1);
    }
    __syncthreads();
    for (int i = threadIdx.x; i < NBS; i += 256) {
        int c = lcnt[i];
        if (c) atomicAdd(&gcnt[i * PAD], c);
    }
}

// ---------- 2. exclusive scan of 7816 counts (single block) ----------
__global__ __launch_bounds__(1024) void scan_kernel(
    const int* __restrict__ gcnt, int* __restrict__ start,
    int* __restrict__ cursor, int nnz)
{
    __shared__ int s[1024];
    int t = threadIdx.x;
    int loc[8]; int sum = 0;
    #pragma unroll
    for (int j = 0; j < 8; j++) {
        int i = t * 8 + j;
        int c = (i < NBS) ? gcnt[i * PAD] : 0;
        loc[j] = sum; sum += c;
    }
    s[t] = sum; __syncthreads();
    int v = sum;
    for (int off = 1; off < 1024; off <<= 1) {
        int add = (t >= off) ? s[t - off] : 0;
        __syncthreads();
        s[t] += add;
        __syncthreads();
    }
    int base = s[t] - v;
    #pragma unroll
    for (int j = 0; j < 8; j++) {
        int i = t * 8 + j;
        if (i < NBS) { int p = base + loc[j]; start[i] = p; cursor[i * PAD] = p; }
    }
    if (t == 0) start[NBS] = nnz;
}

// ---------- 3. bin-scatter: write records grouped by bucket ----------
// thin record: (lrow<<24) | edge_id   (requires nnz < 2^24)
__global__ __launch_bounds__(256) void scatter_thin(
    const int* __restrict__ rows, int* __restrict__ cursor,
    unsigned* __restrict__ recs, int nnz)
{
    int stride = gridDim.x * 256;
    for (int e = blockIdx.x * 256 + threadIdx.x; e < nnz; e += stride) {
        int r = rows[e];
        int bs = ((r >> 8) << 2) | ((e >> 12) & 3);
        int pos = atomicAdd(&cursor[bs * PAD], 1);
        recs[pos] = ((unsigned)(r & 255) << 24) | (unsigned)e;
    }
}

// fat record: { (lrow<<19)|col , val }  — no indirection in accumulate
__global__ __launch_bounds__(256) void scatter_fat(
    const int* __restrict__ rows, const int* __restrict__ cols,
    const float* __restrict__ vals, int* __restrict__ cursor,
    uint2* __restrict__ recs, int nnz)
{
    int stride = gridDim.x * 256;
    for (int e = blockIdx.x * 256 + threadIdx.x; e < nnz; e += stride) {
        int r = rows[e];
        int c = cols[e];
        float v = vals[e];
        int bs = ((r >> 8) << 2) | ((e >> 12) & 3);
        int pos = atomicAdd(&cursor[bs * PAD], 1);
        uint2 rec;
        rec.x = ((unsigned)(r & 255) << 19) | (unsigned)c;
        rec.y = __float_as_uint(v);
        recs[pos] = rec;
    }
}

// ---------- 4. per-bucket accumulate into LDS ----------
// Records are wave-uniform (scalar loads, SALU decode); each edge does one
// 256B coalesced embedding gather + one conflict-free ds_add_f32.
__global__ __launch_bounds__(256) void accum_thin(
    const float* __restrict__ users_emb, const float* __restrict__ items_emb,
    const float* __restrict__ vals, const int* __restrict__ cols,
    const unsigned* __restrict__ recs, const int* __restrict__ start,
    float* __restrict__ agg)
{
    __shared__ float acc[RPB * D];            // 64 KB -> 2 blocks/CU
    int tid = threadIdx.x;
    f32x4 z = {0.f, 0.f, 0.f, 0.f};
    for (int i = tid; i < RPB * D / 4; i += 256) ((f32x4*)acc)[i] = z;
    __syncthreads();
    int b = blockIdx.x;
    int s0 = start[b * NS], s1 = start[b * NS + NS];
    int lane = tid & 63, wid = tid >> 6;
    int per = (s1 - s0 + 3) >> 2;
    int a0 = s0 + wid * per;
    int a1 = a0 + per; if (a1 > s1) a1 = s1;
    float* accl = acc + lane;
    for (int idx = a0; idx < a1; idx++) {
        unsigned rec = recs[idx];                         // uniform -> s_load
        int e    = (int)(rec & 0xFFFFFFu);
        int lrow = (int)(rec >> 24);
        int c    = cols[e];                               // uniform -> s_load
        float v  = vals[e];
        const float* src = (c < NUM_USER) ? users_emb + (size_t)c * D
                                          : items_emb + (size_t)(c - NUM_USER) * D;
        atomicAdd(accl + lrow * D, v * src[lane]);        // bank = lane%32: free
    }
    __syncthreads();
    int row0 = b * RPB;
    int nr = NTOT - row0; if (nr > RPB) nr = RPB;
    float4* dst = (float4*)(agg + (size_t)row0 * D);
    const float4* srcl = (const float4*)acc;
    for (int i = tid; i < nr * (D / 4); i += 256) dst[i] = srcl[i];
}

__global__ __launch_bounds__(256) void accum_fat(
    const float* __restrict__ users_emb, const float* __restrict__ items_emb,
    const uint2* __restrict__ recs, const int* __restrict__ start,
    float* __restrict__ agg)
{
    __shared__ float acc[RPB * D];
    int tid = threadIdx.x;
    f32x4 z = {0.f, 0.f, 0.f, 0.f};
    for (int i = tid; i < RPB * D / 4; i += 256) ((f32x4*)acc)[i] = z;
    __syncthreads();
    int b = blockIdx.x;
    int s0 = start[b * NS], s1 = start[b * NS + NS];
    int lane = tid & 63, wid = tid >> 6;
    int per = (s1 - s0 + 3) >> 2;
    int a0 = s0 + wid * per;
    int a1 = a0 + per; if (a1 > s1) a1 = s1;
    float* accl = acc + lane;
    for (int idx = a0; idx < a1; idx++) {
        uint2 rec = recs[idx];                            // uniform -> s_load_dwordx2
        int c    = (int)(rec.x & 0x7FFFFu);
        int lrow = (int)(rec.x >> 19);
        float v  = __uint_as_float(rec.y);
        const float* src = (c < NUM_USER) ? users_emb + (size_t)c * D
                                          : items_emb + (size_t)(c - NUM_USER) * D;
        atomicAdd(accl + lrow * D, v * src[lane]);
    }
    __syncthreads();
    int row0 = b * RPB;
    int nr = NTOT - row0; if (nr > RPB) nr = RPB;
    float4* dst = (float4*)(agg + (size_t)row0 * D);
    const float4* srcl = (const float4*)acc;
    for (int i = tid; i < nr * (D / 4); i += 256) dst[i] = srcl[i];
}

// ---------- 5. in-place out = leaky_relu(agg @ w) via bf16 MFMA ----------
__global__ __launch_bounds__(256) void gemm_kernel(
    float* __restrict__ out, const float* __restrict__ w)
{
    __shared__ short wt[D * 72];   // wt[n*72+k] bf16, padded (18.4 KB)
    int tid = threadIdx.x;
    for (int i = tid; i < D * D; i += 256) {
        int k = i >> 6, n = i & 63;
        wt[n * 72 + k] = f2bf(w[i]);
    }
    __syncthreads();
    int wid = tid >> 6, lane = tid & 63;
    int row0 = blockIdx.x * 64 + wid * 16;
    if (row0 >= NTOT) return;
    int quad = lane >> 4, mrow = lane & 15;

    // A fragments: A[m=lane&15][k=quad*8+j] (+32 for second mfma)
    bf16x8 a[2];
    const float* arow = out + (size_t)(row0 + mrow) * D;
    #pragma unroll
    for (int kh = 0; kh < 2; kh++) {
        int kb = kh * 32 + quad * 8;
        float4 f0 = *(const float4*)(arow + kb);
        float4 f1 = *(const float4*)(arow + kb + 4);
        bf16x8 t;
        t[0] = f2bf(f0.x); t[1] = f2bf(f0.y); t[2] = f2bf(f0.z); t[3] = f2bf(f0.w);
        t[4] = f2bf(f1.x); t[5] = f2bf(f1.y); t[6] = f2bf(f1.z); t[7] = f2bf(f1.w);
        a[kh] = t;
    }
    f32x4 accv[4];
    #pragma unroll
    for (int ct = 0; ct < 4; ct++) accv[ct] = (f32x4){0.f, 0.f, 0.f, 0.f};
    #pragma unroll
    for (int ct = 0; ct < 4; ct++) {
        int n = ct * 16 + mrow;
        #pragma unroll
        for (int kh = 0; kh < 2; kh++) {
            int kb = kh * 32 + quad * 8;
            bf16x8 bf = *(bf16x8*)(wt + n * 72 + kb);  // 16B aligned LDS read
            accv[ct] = __builtin_amdgcn_mfma_f32_16x16x32_bf16(a[kh], bf, accv[ct], 0, 0, 0);
        }
    }
    // C/D layout: col = lane&15, row = quad*4 + reg
    #pragma unroll
    for (int ct = 0; ct < 4; ct++) {
        #pragma unroll
        for (int r = 0; r < 4; r++) {
            float vv = accv[ct][r];
            vv = vv > 0.f ? vv : 0.2f * vv;
            out[(size_t)(row0 + quad * 4 + r) * D + ct * 16 + mrow] = vv;
        }
    }
}

extern "C" void kernel_launch(void* const* d_in, const int* in_sizes, int n_in,
                              void* d_out, int out_size, void* d_ws, size_t ws_size,
                              hipStream_t stream) {
    const float* users_emb = (const float*)d_in[0];
    const float* items_emb = (const float*)d_in[1];
    const float* vals      = (const float*)d_in[2];
    const float* w         = (const float*)d_in[3];
    const int*   rows      = (const int*)d_in[4];
    const int*   cols      = (const int*)d_in[5];
    float* out = (float*)d_out;
    int nnz = in_sizes[2];

    // ws: gcnt@0 (0.5MB pad), start@1MB (31KB), cursor@2MB (0.5MB), recs@3MB
    char* wsb = (char*)d_ws;
    int* gcnt   = (int*)(wsb);
    int* start  = (int*)(wsb + (1ull << 20));
    int* cursor = (int*)(wsb + (2ull << 20));
    void* recs  = (void*)(wsb + (3ull << 20));
    bool fat = ws_size >= (3ull << 20) + (size_t)nnz * sizeof(uint2);

    hipMemsetAsync(gcnt, 0, (size_t)NBS * PAD * sizeof(int), stream);
    hist_kernel<<<256, 256, 0, stream>>>(rows, gcnt, nnz);
    scan_kernel<<<1, 1024, 0, stream>>>(gcnt, start, cursor, nnz);
    if (fat) {
        scatter_fat<<<2048, 256, 0, stream>>>(rows, cols, vals, cursor,
                                              (uint2*)recs, nnz);
        accum_fat<<<NB, 256, 0, stream>>>(users_emb, items_emb,
                                          (const uint2*)recs, start, out);
    } else {
        scatter_thin<<<2048, 256, 0, stream>>>(rows, cursor,
                                               (unsigned*)recs, nnz);
        accum_thin<<<NB, 256, 0, stream>>>(users_emb, items_emb, vals, cols,
                                           (const unsigned*)recs, start, out);
    }
    gemm_kernel<<<(NTOT + 63) / 64, 256, 0, stream>>>(out, w);
}